// Round 18
// baseline (533.865 us; speedup 1.0000x reference)
//
#include <hip/hip_runtime.h>
#include <math.h>

#define B_ 32
#define INLEN 10
#define LIN_ 16384
#define NPOLY 12
#define MM 6
#define CH 20
#define RECEPT 25
#define L0 16434      // length after first conv
#define TT2 240       // final outputs per tile per pair-kernel (multiple of 6)
#define XS_LEN 264    // layer-A input width = TT2 + 24 (proven R13/R16/R17 tile)
#define XS_PAD 265    // odd stride -> bank-conflict-free strided reads
#define NWA 43        // (264-12)/6+1 windows, layer A
#define NWB 41        // (252-12)/6+1 windows, layer B
#define LXS_PAD 121   // odd stride
#define CCHUNK 5      // ci-chunk (R5 spill fix)
#define CQ 5          // output channels per 256-thread QUARTER (CH/4)
#define INW 266       // raw-input tile width for fused first conv

__device__ __forceinline__ float gelu_exact(float x) {
    return 0.5f * x * (1.0f + erff(x * 0.70710678118654752440f));
}

// ---------------- pair kernel: 2 layers (+ first conv / + head) per dispatch ----------------
// R18 = R17 pair structure (proven 473 us total, VGPR 40, occ 59%) at 1024 THREADS/BLOCK.
// Mechanism: at 512t residency pins at ~2.3 blocks/CU (achieved ~0.79x static across
// R2/R7/R13) -> 18.9 waves/CU = 59% occ. At 1024t, TWO resident blocks = 32 waves = 100%;
// even 1.6 achieved = 80%. LDS unchanged (2 x 45.6K = 91K <= 160K). Channel split goes
// halves -> quarters (q = tid>>8, 5 channels each): per-thread live state halves again
// (~30 VGPR), safe under the 64-VGPR cliff (R12) even with launch_bounds(1024,2)'s
// 64-VGPR RA target. Geometry/stages/barriers byte-equivalent to R17.
//   PAIR 0: first conv + layer0 + layer1 -> writes 42 MB once.
//   PAIR 1: layer2 + layer3 + head (4x32 hidden units, 4-way partial reduce in dead lxs)
//           -> writes 2 MB.
// Lessons kept: CCHUNK=5 + unroll 1 (R5); readfirstlane'd quarter (R6); odd LDS strides;
// straight-line compile-time-constant bodies (R8/R10 fused-loop collapse avoided).
template<int PAIR>
__global__ __launch_bounds__(1024, 2)
void k_pair(const float* __restrict__ xin, float* __restrict__ xout,
            const float* __restrict__ conv_a, const float* __restrict__ conv_b,
            const float* __restrict__ lin_m, const float* __restrict__ fd,
            const float* __restrict__ fr,
            const float* __restrict__ in0, const float* __restrict__ wf,
            const float* __restrict__ w11, const float* __restrict__ wout) {
    constexpr int LA_IN  = (PAIR == 0) ? L0 : (L0 - 24);   // layer-A input length (global)
    constexpr int LA_OUT = LA_IN - 12;
    constexpr int LB_OUT = LA_OUT - 12;
    constexpr int WOFF   = CH * CH * 3;
    constexpr int MOFF   = CH * MM * MM;

    const int tid  = threadIdx.x;          // 0..1023
    const int t    = tid & 255;            // position within quarter
    const int q    = __builtin_amdgcn_readfirstlane(tid >> 8);   // 0..3, wave-uniform
    const int cob  = q * CQ;               // SGPR: first output channel of this quarter
    const int t0   = blockIdx.x * TT2;     // multiple of 6
    const int b    = blockIdx.y;

    const float* wAa = conv_a + (2 * PAIR)     * WOFF + cob * CH * 3;
    const float* wBa = conv_b + (2 * PAIR)     * WOFF + cob * CH * 3;
    const float* wAb = conv_a + (2 * PAIR + 1) * WOFF + cob * CH * 3;
    const float* wBb = conv_b + (2 * PAIR + 1) * WOFF + cob * CH * 3;

    __shared__ float xs[CH][XS_PAD];       // x -> g -> next x (in place, barrier-guarded)
    __shared__ float lxs[NWA][LXS_PAD];    // Legendre coeffs; also raw-input stage (PAIR0)
                                           // and head partial-sum buffer (PAIR1)
    __shared__ float lm_s[MOFF];           // current layer's lin_m
    __shared__ float fr_s[MM * NPOLY];     // filt_r (layer-invariant)

    for (int i = tid; i < MOFF; i += 1024) lm_s[i] = lin_m[(2 * PAIR) * MOFF + i];
    for (int i = tid; i < MM * NPOLY; i += 1024) fr_s[i] = fr[i];

    // ---------------- stage IN -> xs[0..264) ----------------
    if constexpr (PAIR == 0) {
        // raw input tile (wrap) into dead lxs region, then 3-tap first conv -> xs
        float* inps = &lxs[0][0];                       // 10*266 = 2660 <= 43*121
        const float* inb = in0 + (size_t)b * INLEN * LIN_;
        for (int i = tid; i < INLEN * INW; i += 1024) {
            int ci = i / INW, qq = i - ci * INW;
            int gq = t0 + qq - RECEPT;
            gq = (gq < 0) ? gq + LIN_ : (gq >= LIN_ ? gq - LIN_ : gq);
            inps[i] = inb[(size_t)ci * LIN_ + gq];
        }
        __syncthreads();
        const float* wfh = wf + cob * INLEN * 3;        // SGPR base -> s_load weights
        for (int p = t; p < XS_LEN; p += 256) {
            float acc[CQ];
#pragma unroll
            for (int co = 0; co < CQ; ++co) acc[co] = 0.f;
#pragma unroll 1
            for (int cig = 0; cig < INLEN; cig += CCHUNK) {
                float xw[CCHUNK][3];
#pragma unroll
                for (int j = 0; j < CCHUNK; ++j) {
                    xw[j][0] = inps[(cig + j) * INW + p];
                    xw[j][1] = inps[(cig + j) * INW + p + 1];
                    xw[j][2] = inps[(cig + j) * INW + p + 2];
                }
#pragma unroll
                for (int co = 0; co < CQ; ++co) {
                    float a = acc[co];
#pragma unroll
                    for (int j = 0; j < CCHUNK; ++j)
#pragma unroll
                        for (int k = 0; k < 3; ++k)
                            a = fmaf(xw[j][k], wfh[(co * INLEN + cig + j) * 3 + k], a);
                    acc[co] = a;
                }
            }
            const bool live = (t0 + p < L0);
#pragma unroll
            for (int co = 0; co < CQ; ++co) xs[cob + co][p] = live ? acc[co] : 0.f;
        }
        __syncthreads();    // xs ready; inps region dead
    } else {
        const float* xb = xin + (size_t)b * CH * LA_IN;
        for (int i = tid; i < CH * XS_LEN; i += 1024) {
            int c = i / XS_LEN, p = i - c * XS_LEN;
            int gp = t0 + p;
            xs[c][p] = (gp < LA_IN) ? xb[(size_t)c * LA_IN + gp] : 0.f;
        }
        __syncthreads();
    }

    float gv[CQ];
    float outv[CQ];

    // ================= LAYER A (input width 264) =================
    for (int item = tid; item < NWA * CH; item += 1024) {       // C1
        int wl = item / CH, c = item - wl * CH;
        float xv[NPOLY];
#pragma unroll
        for (int k = 0; k < NPOLY; ++k) xv[k] = xs[c][6 * wl + k];
#pragma unroll
        for (int m = 0; m < MM; ++m) {
            float acc = 0.f;
#pragma unroll
            for (int k = 0; k < NPOLY; ++k)
                acc = fmaf(xv[k], fd[m * NPOLY + k], acc);
            lxs[wl][m * CH + c] = acc * 0.5f;
        }
    }
    if (t < XS_LEN - 10) {                                      // B (width 254)
#pragma unroll
        for (int co = 0; co < CQ; ++co) gv[co] = 0.f;
#pragma unroll 1
        for (int cig = 0; cig < CH; cig += CCHUNK) {
            float xw[CCHUNK][3];
#pragma unroll
            for (int j = 0; j < CCHUNK; ++j) {
                xw[j][0] = xs[cig + j][t + 4];
                xw[j][1] = xs[cig + j][t + 5];
                xw[j][2] = xs[cig + j][t + 6];
            }
#pragma unroll
            for (int co = 0; co < CQ; ++co) {
                float acc = gv[co];
#pragma unroll
                for (int j = 0; j < CCHUNK; ++j)
#pragma unroll
                    for (int k = 0; k < 3; ++k)
                        acc = fmaf(xw[j][k], wAa[(co * CH + cig + j) * 3 + k], acc);
                gv[co] = acc;
            }
        }
#pragma unroll
        for (int co = 0; co < CQ; ++co) gv[co] = gelu_exact(gv[co]);
    }
    __syncthreads();
    if (t < XS_LEN - 10) {
#pragma unroll
        for (int co = 0; co < CQ; ++co) xs[cob + co][t] = gv[co];
    }
    for (int item = tid; item < NWA * CH; item += 1024) {       // C2
        int wl = item / CH, g = item - wl * CH;
        float iv[MM], ov[MM];
#pragma unroll
        for (int i = 0; i < MM; ++i) iv[i] = lxs[wl][g * MM + i];
#pragma unroll
        for (int o = 0; o < MM; ++o) {
            float acc = 0.f;
#pragma unroll
            for (int i = 0; i < MM; ++i)
                acc = fmaf(iv[i], lm_s[(g * MM + o) * MM + i], acc);
            ov[o] = acc;
        }
#pragma unroll
        for (int o = 0; o < MM; ++o) lxs[wl][g * MM + o] = ov[o];
    }
    __syncthreads();
    const bool vdA = (t < XS_LEN - 12) && (t0 + t < LA_OUT);    // D (252 outputs)
    if (vdA) {
        float acc[CQ];
#pragma unroll
        for (int co = 0; co < CQ; ++co) acc[co] = 0.f;
#pragma unroll 1
        for (int cig = 0; cig < CH; cig += CCHUNK) {
            float aw[CCHUNK][3];
#pragma unroll
            for (int j = 0; j < CCHUNK; ++j) {
                aw[j][0] = xs[cig + j][t];
                aw[j][1] = xs[cig + j][t + 1];
                aw[j][2] = xs[cig + j][t + 2];
            }
#pragma unroll
            for (int co = 0; co < CQ; ++co) {
                float a = acc[co];
#pragma unroll
                for (int j = 0; j < CCHUNK; ++j)
#pragma unroll
                    for (int k = 0; k < 3; ++k)
                        a = fmaf(aw[j][k], wBa[(co * CH + cig + j) * 3 + k], a);
                acc[co] = a;
            }
        }
        const int r1  = t % 6;
        const int wl1 = t / 6 + 1;                              // <= 42 < NWA
        float frA[MM], frB[MM];
#pragma unroll
        for (int m = 0; m < MM; ++m) {
            frA[m] = fr_s[m * NPOLY + r1];
            frB[m] = fr_s[m * NPOLY + r1 + 6];
        }
#pragma unroll
        for (int co = 0; co < CQ; ++co) {
            float rec = 0.f;
#pragma unroll
            for (int m = 0; m < MM; ++m) {
                rec = fmaf(lxs[wl1][m * CH + cob + co], frA[m], rec);
                rec = fmaf(lxs[wl1 - 1][m * CH + cob + co], frB[m], rec);
            }
            outv[co] = gelu_exact(acc[co] + rec);
        }
    }
    __syncthreads();               // all layer-A reads of xs/lxs done
    if (vdA) {
#pragma unroll
        for (int co = 0; co < CQ; ++co) xs[cob + co][t] = outv[co];
    }
    for (int i = tid; i < MOFF; i += 1024)                      // next layer's lin_m
        lm_s[i] = lin_m[(2 * PAIR + 1) * MOFF + i];
    __syncthreads();               // new x + lm visible

    // ================= LAYER B (input width 252) =================
    for (int item = tid; item < NWB * CH; item += 1024) {       // C1
        int wl = item / CH, c = item - wl * CH;
        float xv[NPOLY];
#pragma unroll
        for (int k = 0; k < NPOLY; ++k) xv[k] = xs[c][6 * wl + k];
#pragma unroll
        for (int m = 0; m < MM; ++m) {
            float acc = 0.f;
#pragma unroll
            for (int k = 0; k < NPOLY; ++k)
                acc = fmaf(xv[k], fd[m * NPOLY + k], acc);
            lxs[wl][m * CH + c] = acc * 0.5f;
        }
    }
    if (t < XS_LEN - 22) {                                      // B (width 242)
#pragma unroll
        for (int co = 0; co < CQ; ++co) gv[co] = 0.f;
#pragma unroll 1
        for (int cig = 0; cig < CH; cig += CCHUNK) {
            float xw[CCHUNK][3];
#pragma unroll
            for (int j = 0; j < CCHUNK; ++j) {
                xw[j][0] = xs[cig + j][t + 4];
                xw[j][1] = xs[cig + j][t + 5];
                xw[j][2] = xs[cig + j][t + 6];
            }
#pragma unroll
            for (int co = 0; co < CQ; ++co) {
                float acc = gv[co];
#pragma unroll
                for (int j = 0; j < CCHUNK; ++j)
#pragma unroll
                    for (int k = 0; k < 3; ++k)
                        acc = fmaf(xw[j][k], wAb[(co * CH + cig + j) * 3 + k], acc);
                gv[co] = acc;
            }
        }
#pragma unroll
        for (int co = 0; co < CQ; ++co) gv[co] = gelu_exact(gv[co]);
    }
    __syncthreads();
    if (t < XS_LEN - 22) {
#pragma unroll
        for (int co = 0; co < CQ; ++co) xs[cob + co][t] = gv[co];
    }
    for (int item = tid; item < NWB * CH; item += 1024) {       // C2
        int wl = item / CH, g = item - wl * CH;
        float iv[MM], ov[MM];
#pragma unroll
        for (int i = 0; i < MM; ++i) iv[i] = lxs[wl][g * MM + i];
#pragma unroll
        for (int o = 0; o < MM; ++o) {
            float acc = 0.f;
#pragma unroll
            for (int i = 0; i < MM; ++i)
                acc = fmaf(iv[i], lm_s[(g * MM + o) * MM + i], acc);
            ov[o] = acc;
        }
#pragma unroll
        for (int o = 0; o < MM; ++o) lxs[wl][g * MM + o] = ov[o];
    }
    __syncthreads();
    const bool vdB = (t < TT2) && (t0 + t < LB_OUT);            // D (240 outputs)
    if (vdB) {
        float acc[CQ];
#pragma unroll
        for (int co = 0; co < CQ; ++co) acc[co] = 0.f;
#pragma unroll 1
        for (int cig = 0; cig < CH; cig += CCHUNK) {
            float aw[CCHUNK][3];
#pragma unroll
            for (int j = 0; j < CCHUNK; ++j) {
                aw[j][0] = xs[cig + j][t];
                aw[j][1] = xs[cig + j][t + 1];
                aw[j][2] = xs[cig + j][t + 2];
            }
#pragma unroll
            for (int co = 0; co < CQ; ++co) {
                float a = acc[co];
#pragma unroll
                for (int j = 0; j < CCHUNK; ++j)
#pragma unroll
                    for (int k = 0; k < 3; ++k)
                        a = fmaf(aw[j][k], wBb[(co * CH + cig + j) * 3 + k], a);
                acc[co] = a;
            }
        }
        const int r1  = t % 6;
        const int wl1 = t / 6 + 1;                              // <= 40 < NWB
        float frA[MM], frB[MM];
#pragma unroll
        for (int m = 0; m < MM; ++m) {
            frA[m] = fr_s[m * NPOLY + r1];
            frB[m] = fr_s[m * NPOLY + r1 + 6];
        }
#pragma unroll
        for (int co = 0; co < CQ; ++co) {
            float rec = 0.f;
#pragma unroll
            for (int m = 0; m < MM; ++m) {
                rec = fmaf(lxs[wl1][m * CH + cob + co], frA[m], rec);
                rec = fmaf(lxs[wl1 - 1][m * CH + cob + co], frB[m], rec);
            }
            outv[co] = gelu_exact(acc[co] + rec);
        }
    }

    if constexpr (PAIR == 0) {
        if (vdB) {
            float* xnb = xout + (size_t)b * CH * LB_OUT + (size_t)cob * LB_OUT;
#pragma unroll
            for (int co = 0; co < CQ; ++co)
                xnb[(size_t)co * LB_OUT + t0 + t] = outv[co];
        }
    } else {
        // fused final head: gelu(20->128) -> 128->1, sliced to 16384; 32 hidden/quarter
        __syncthreads();   // all D reads of xs/lxs done
        if (vdB) {
#pragma unroll
            for (int co = 0; co < CQ; ++co) xs[cob + co][t] = outv[co];
        }
        __syncthreads();   // layer-3 output visible in xs
        const bool vf = (t < TT2) && (t0 + t < LIN_);
        float* pb = &lxs[0][0];                    // lxs dead -> partial-sum buffer (1024)
        if (vf) {
            float xv[CH];
#pragma unroll
            for (int c = 0; c < CH; ++c) xv[c] = xs[c][t];
            const float* w11h  = w11 + (size_t)(q * 32) * CH;   // SGPR base
            const float* wouth = wout + q * 32;
            float partial = 0.f;
#pragma unroll 1
            for (int h = 0; h < 32; h += 2) {
                float hv0 = 0.f, hv1 = 0.f;
#pragma unroll
                for (int c = 0; c < CH; ++c) {
                    hv0 = fmaf(xv[c], w11h[h * CH + c], hv0);
                    hv1 = fmaf(xv[c], w11h[(h + 1) * CH + c], hv1);
                }
                partial = fmaf(gelu_exact(hv0), wouth[h], partial);
                partial = fmaf(gelu_exact(hv1), wouth[h + 1], partial);
            }
            pb[q * 256 + t] = partial;
        }
        __syncthreads();
        if (vf && q == 0)
            xout[(size_t)b * LIN_ + t0 + t] =
                (pb[t] + pb[256 + t]) + (pb[512 + t] + pb[768 + t]);
    }
}

extern "C" void kernel_launch(void* const* d_in, const int* in_sizes, int n_in,
                              void* d_out, int out_size, void* d_ws, size_t ws_size,
                              hipStream_t stream) {
    const float* input   = (const float*)d_in[0];
    const float* w_first = (const float*)d_in[1];
    const float* conv_a  = (const float*)d_in[2];
    const float* conv_b  = (const float*)d_in[3];
    const float* lin_m   = (const float*)d_in[4];
    const float* w11     = (const float*)d_in[5];
    const float* w_out   = (const float*)d_in[6];
    const float* filt_d  = (const float*)d_in[7];
    const float* filt_r  = (const float*)d_in[8];
    float* out = (float*)d_out;

    float* xA = (float*)d_ws;   // intermediate: layer-1 output, 32*20*16410 floats = 42 MB

    {
        dim3 grid(((L0 - 24) + TT2 - 1) / TT2, B_);    // 69 tiles covering 16410
        k_pair<0><<<grid, 1024, 0, stream>>>(nullptr, xA, conv_a, conv_b, lin_m,
                                             filt_d, filt_r, input, w_first,
                                             nullptr, nullptr);
    }
    {
        dim3 grid((LIN_ + TT2 - 1) / TT2, B_);         // 69 tiles covering 16384
        k_pair<1><<<grid, 1024, 0, stream>>>(xA, out, conv_a, conv_b, lin_m,
                                             filt_d, filt_r, nullptr, nullptr,
                                             w11, w_out);
    }
}

// Round 19
// 475.606 us; speedup vs baseline: 1.1225x; 1.1225x over previous
//
#include <hip/hip_runtime.h>
#include <math.h>

#define B_ 32
#define INLEN 10
#define LIN_ 16384
#define NPOLY 12
#define MM 6
#define CH 20
#define RECEPT 25
#define L0 16434      // length after first conv
#define TT2 240       // final outputs per tile per pair-kernel (multiple of 6)
#define XS_LEN 264    // layer-A input width = TT2 + 24 (proven R13/R16 tile)
#define XS_PAD 265    // odd stride -> bank-conflict-free strided reads
#define NWA 43        // (264-12)/6+1 windows, layer A
#define NWB 41        // (252-12)/6+1 windows, layer B
#define LXS_PAD 121   // odd stride
#define CCHUNK 5      // ci-chunk (R5 spill fix)
#define COH 10        // output channels per 256-thread half
#define INW 266       // raw-input tile width for fused first conv

__device__ __forceinline__ float gelu_exact(float x) {
    return 0.5f * x * (1.0f + erff(x * 0.70710678118654752440f));
}

// ---------------- pair kernel: 2 layers (+ first conv / + head) per dispatch ----------------
// R19 = R17 verbatim (TERMINAL REVERT; best verified: 473.6 us total, VGPR 40, occ 59%).
// R18 post-mortem: 1024-thread blocks collapsed residency to ~0.9 blocks/CU (occ 44.7%,
// +60 us) -- block-size scaling of the residency cap, same signature as R8/R10. All
// occupancy/vectorization/fusion-depth levers now falsified with counter evidence:
//   LDS size !-> residency (R11); 4-layer loop -> collapse (R8/R10); 1024t -> collapse
//   (R18); float2 LDS -> VGPR-64 cliff (R12); occupancy hints -> spills (R2/R3).
//   PAIR 0: first conv (MODE0 staging) + layer0 + layer1 -> writes 42 MB once.
//   PAIR 1: layer2 + layer3 + head (MODE2 tail) -> writes 2 MB.
// Lessons kept: __launch_bounds__(512,2) only; CCHUNK=5 + unroll 1; readfirstlane'd cob;
// odd LDS strides; straight-line compile-time-constant bodies; lm_s reloaded between
// layers inside the writeback barrier gap.
template<int PAIR>
__global__ __launch_bounds__(512, 2)
void k_pair(const float* __restrict__ xin, float* __restrict__ xout,
            const float* __restrict__ conv_a, const float* __restrict__ conv_b,
            const float* __restrict__ lin_m, const float* __restrict__ fd,
            const float* __restrict__ fr,
            const float* __restrict__ in0, const float* __restrict__ wf,
            const float* __restrict__ w11, const float* __restrict__ wout) {
    constexpr int LA_IN  = (PAIR == 0) ? L0 : (L0 - 24);   // layer-A input length (global)
    constexpr int LA_OUT = LA_IN - 12;
    constexpr int LB_OUT = LA_OUT - 12;
    constexpr int WOFF   = CH * CH * 3;
    constexpr int MOFF   = CH * MM * MM;

    const int tid  = threadIdx.x;          // 0..511
    const int t    = tid & 255;            // position within half
    const int half = __builtin_amdgcn_readfirstlane(tid >> 8);
    const int cob  = half * COH;           // SGPR: first output channel of this half
    const int t0   = blockIdx.x * TT2;     // multiple of 6
    const int b    = blockIdx.y;

    const float* wAa = conv_a + (2 * PAIR)     * WOFF + cob * CH * 3;
    const float* wBa = conv_b + (2 * PAIR)     * WOFF + cob * CH * 3;
    const float* wAb = conv_a + (2 * PAIR + 1) * WOFF + cob * CH * 3;
    const float* wBb = conv_b + (2 * PAIR + 1) * WOFF + cob * CH * 3;

    __shared__ float xs[CH][XS_PAD];       // x -> g -> next x (in place, barrier-guarded)
    __shared__ float lxs[NWA][LXS_PAD];    // Legendre coeffs; also raw-input stage (PAIR0)
                                           // and head partial-sum buffer (PAIR1)
    __shared__ float lm_s[MOFF];           // current layer's lin_m
    __shared__ float fr_s[MM * NPOLY];     // filt_r (layer-invariant)

    for (int i = tid; i < MOFF; i += 512) lm_s[i] = lin_m[(2 * PAIR) * MOFF + i];
    for (int i = tid; i < MM * NPOLY; i += 512) fr_s[i] = fr[i];

    // ---------------- stage IN -> xs[0..264) ----------------
    if constexpr (PAIR == 0) {
        // raw input tile (wrap) into dead lxs region, then 3-tap first conv -> xs
        float* inps = &lxs[0][0];                       // 10*266 = 2660 <= 43*121
        const float* inb = in0 + (size_t)b * INLEN * LIN_;
        for (int i = tid; i < INLEN * INW; i += 512) {
            int ci = i / INW, q = i - ci * INW;
            int gq = t0 + q - RECEPT;
            gq = (gq < 0) ? gq + LIN_ : (gq >= LIN_ ? gq - LIN_ : gq);
            inps[i] = inb[(size_t)ci * LIN_ + gq];
        }
        __syncthreads();
        const float* wfh = wf + cob * INLEN * 3;        // SGPR base -> s_load weights
        for (int p = t; p < XS_LEN; p += 256) {
            float acc[COH];
#pragma unroll
            for (int co = 0; co < COH; ++co) acc[co] = 0.f;
#pragma unroll 1
            for (int cig = 0; cig < INLEN; cig += CCHUNK) {
                float xw[CCHUNK][3];
#pragma unroll
                for (int j = 0; j < CCHUNK; ++j) {
                    xw[j][0] = inps[(cig + j) * INW + p];
                    xw[j][1] = inps[(cig + j) * INW + p + 1];
                    xw[j][2] = inps[(cig + j) * INW + p + 2];
                }
#pragma unroll
                for (int co = 0; co < COH; ++co) {
                    float a = acc[co];
#pragma unroll
                    for (int j = 0; j < CCHUNK; ++j)
#pragma unroll
                        for (int k = 0; k < 3; ++k)
                            a = fmaf(xw[j][k], wfh[(co * INLEN + cig + j) * 3 + k], a);
                    acc[co] = a;
                }
            }
            const bool live = (t0 + p < L0);
#pragma unroll
            for (int co = 0; co < COH; ++co) xs[cob + co][p] = live ? acc[co] : 0.f;
        }
        __syncthreads();    // xs ready; inps region dead
    } else {
        const float* xb = xin + (size_t)b * CH * LA_IN;
        for (int i = tid; i < CH * XS_LEN; i += 512) {
            int c = i / XS_LEN, p = i - c * XS_LEN;
            int gp = t0 + p;
            xs[c][p] = (gp < LA_IN) ? xb[(size_t)c * LA_IN + gp] : 0.f;
        }
        __syncthreads();
    }

    float gv[COH];
    float outv[COH];

    // ================= LAYER A (input width 264) =================
    for (int item = tid; item < NWA * CH; item += 512) {        // C1
        int wl = item / CH, c = item - wl * CH;
        float xv[NPOLY];
#pragma unroll
        for (int k = 0; k < NPOLY; ++k) xv[k] = xs[c][6 * wl + k];
#pragma unroll
        for (int m = 0; m < MM; ++m) {
            float acc = 0.f;
#pragma unroll
            for (int k = 0; k < NPOLY; ++k)
                acc = fmaf(xv[k], fd[m * NPOLY + k], acc);
            lxs[wl][m * CH + c] = acc * 0.5f;
        }
    }
    if (t < XS_LEN - 10) {                                      // B (width 254)
#pragma unroll
        for (int co = 0; co < COH; ++co) gv[co] = 0.f;
#pragma unroll 1
        for (int cig = 0; cig < CH; cig += CCHUNK) {
            float xw[CCHUNK][3];
#pragma unroll
            for (int j = 0; j < CCHUNK; ++j) {
                xw[j][0] = xs[cig + j][t + 4];
                xw[j][1] = xs[cig + j][t + 5];
                xw[j][2] = xs[cig + j][t + 6];
            }
#pragma unroll
            for (int co = 0; co < COH; ++co) {
                float acc = gv[co];
#pragma unroll
                for (int j = 0; j < CCHUNK; ++j)
#pragma unroll
                    for (int k = 0; k < 3; ++k)
                        acc = fmaf(xw[j][k], wAa[(co * CH + cig + j) * 3 + k], acc);
                gv[co] = acc;
            }
        }
#pragma unroll
        for (int co = 0; co < COH; ++co) gv[co] = gelu_exact(gv[co]);
    }
    __syncthreads();
    if (t < XS_LEN - 10) {
#pragma unroll
        for (int co = 0; co < COH; ++co) xs[cob + co][t] = gv[co];
    }
    for (int item = tid; item < NWA * CH; item += 512) {        // C2
        int wl = item / CH, g = item - wl * CH;
        float iv[MM], ov[MM];
#pragma unroll
        for (int i = 0; i < MM; ++i) iv[i] = lxs[wl][g * MM + i];
#pragma unroll
        for (int o = 0; o < MM; ++o) {
            float acc = 0.f;
#pragma unroll
            for (int i = 0; i < MM; ++i)
                acc = fmaf(iv[i], lm_s[(g * MM + o) * MM + i], acc);
            ov[o] = acc;
        }
#pragma unroll
        for (int o = 0; o < MM; ++o) lxs[wl][g * MM + o] = ov[o];
    }
    __syncthreads();
    const bool vdA = (t < XS_LEN - 12) && (t0 + t < LA_OUT);    // D (252 outputs)
    if (vdA) {
        float acc[COH];
#pragma unroll
        for (int co = 0; co < COH; ++co) acc[co] = 0.f;
#pragma unroll 1
        for (int cig = 0; cig < CH; cig += CCHUNK) {
            float aw[CCHUNK][3];
#pragma unroll
            for (int j = 0; j < CCHUNK; ++j) {
                aw[j][0] = xs[cig + j][t];
                aw[j][1] = xs[cig + j][t + 1];
                aw[j][2] = xs[cig + j][t + 2];
            }
#pragma unroll
            for (int co = 0; co < COH; ++co) {
                float a = acc[co];
#pragma unroll
                for (int j = 0; j < CCHUNK; ++j)
#pragma unroll
                    for (int k = 0; k < 3; ++k)
                        a = fmaf(aw[j][k], wBa[(co * CH + cig + j) * 3 + k], a);
                acc[co] = a;
            }
        }
        const int r1  = t % 6;
        const int wl1 = t / 6 + 1;                              // <= 42 < NWA
        float frA[MM], frB[MM];
#pragma unroll
        for (int m = 0; m < MM; ++m) {
            frA[m] = fr_s[m * NPOLY + r1];
            frB[m] = fr_s[m * NPOLY + r1 + 6];
        }
#pragma unroll
        for (int co = 0; co < COH; ++co) {
            float rec = 0.f;
#pragma unroll
            for (int m = 0; m < MM; ++m) {
                rec = fmaf(lxs[wl1][m * CH + cob + co], frA[m], rec);
                rec = fmaf(lxs[wl1 - 1][m * CH + cob + co], frB[m], rec);
            }
            outv[co] = gelu_exact(acc[co] + rec);
        }
    }
    __syncthreads();               // all layer-A reads of xs/lxs done
    if (vdA) {
#pragma unroll
        for (int co = 0; co < COH; ++co) xs[cob + co][t] = outv[co];
    }
    for (int i = tid; i < MOFF; i += 512)                       // next layer's lin_m
        lm_s[i] = lin_m[(2 * PAIR + 1) * MOFF + i];
    __syncthreads();               // new x + lm visible

    // ================= LAYER B (input width 252) =================
    for (int item = tid; item < NWB * CH; item += 512) {        // C1
        int wl = item / CH, c = item - wl * CH;
        float xv[NPOLY];
#pragma unroll
        for (int k = 0; k < NPOLY; ++k) xv[k] = xs[c][6 * wl + k];
#pragma unroll
        for (int m = 0; m < MM; ++m) {
            float acc = 0.f;
#pragma unroll
            for (int k = 0; k < NPOLY; ++k)
                acc = fmaf(xv[k], fd[m * NPOLY + k], acc);
            lxs[wl][m * CH + c] = acc * 0.5f;
        }
    }
    if (t < XS_LEN - 22) {                                      // B (width 242)
#pragma unroll
        for (int co = 0; co < COH; ++co) gv[co] = 0.f;
#pragma unroll 1
        for (int cig = 0; cig < CH; cig += CCHUNK) {
            float xw[CCHUNK][3];
#pragma unroll
            for (int j = 0; j < CCHUNK; ++j) {
                xw[j][0] = xs[cig + j][t + 4];
                xw[j][1] = xs[cig + j][t + 5];
                xw[j][2] = xs[cig + j][t + 6];
            }
#pragma unroll
            for (int co = 0; co < COH; ++co) {
                float acc = gv[co];
#pragma unroll
                for (int j = 0; j < CCHUNK; ++j)
#pragma unroll
                    for (int k = 0; k < 3; ++k)
                        acc = fmaf(xw[j][k], wAb[(co * CH + cig + j) * 3 + k], acc);
                gv[co] = acc;
            }
        }
#pragma unroll
        for (int co = 0; co < COH; ++co) gv[co] = gelu_exact(gv[co]);
    }
    __syncthreads();
    if (t < XS_LEN - 22) {
#pragma unroll
        for (int co = 0; co < COH; ++co) xs[cob + co][t] = gv[co];
    }
    for (int item = tid; item < NWB * CH; item += 512) {        // C2
        int wl = item / CH, g = item - wl * CH;
        float iv[MM], ov[MM];
#pragma unroll
        for (int i = 0; i < MM; ++i) iv[i] = lxs[wl][g * MM + i];
#pragma unroll
        for (int o = 0; o < MM; ++o) {
            float acc = 0.f;
#pragma unroll
            for (int i = 0; i < MM; ++i)
                acc = fmaf(iv[i], lm_s[(g * MM + o) * MM + i], acc);
            ov[o] = acc;
        }
#pragma unroll
        for (int o = 0; o < MM; ++o) lxs[wl][g * MM + o] = ov[o];
    }
    __syncthreads();
    const bool vdB = (t < TT2) && (t0 + t < LB_OUT);            // D (240 outputs)
    if (vdB) {
        float acc[COH];
#pragma unroll
        for (int co = 0; co < COH; ++co) acc[co] = 0.f;
#pragma unroll 1
        for (int cig = 0; cig < CH; cig += CCHUNK) {
            float aw[CCHUNK][3];
#pragma unroll
            for (int j = 0; j < CCHUNK; ++j) {
                aw[j][0] = xs[cig + j][t];
                aw[j][1] = xs[cig + j][t + 1];
                aw[j][2] = xs[cig + j][t + 2];
            }
#pragma unroll
            for (int co = 0; co < COH; ++co) {
                float a = acc[co];
#pragma unroll
                for (int j = 0; j < CCHUNK; ++j)
#pragma unroll
                    for (int k = 0; k < 3; ++k)
                        a = fmaf(aw[j][k], wBb[(co * CH + cig + j) * 3 + k], a);
                acc[co] = a;
            }
        }
        const int r1  = t % 6;
        const int wl1 = t / 6 + 1;                              // <= 40 < NWB
        float frA[MM], frB[MM];
#pragma unroll
        for (int m = 0; m < MM; ++m) {
            frA[m] = fr_s[m * NPOLY + r1];
            frB[m] = fr_s[m * NPOLY + r1 + 6];
        }
#pragma unroll
        for (int co = 0; co < COH; ++co) {
            float rec = 0.f;
#pragma unroll
            for (int m = 0; m < MM; ++m) {
                rec = fmaf(lxs[wl1][m * CH + cob + co], frA[m], rec);
                rec = fmaf(lxs[wl1 - 1][m * CH + cob + co], frB[m], rec);
            }
            outv[co] = gelu_exact(acc[co] + rec);
        }
    }

    if constexpr (PAIR == 0) {
        if (vdB) {
            float* xnb = xout + (size_t)b * CH * LB_OUT + (size_t)cob * LB_OUT;
#pragma unroll
            for (int co = 0; co < COH; ++co)
                xnb[(size_t)co * LB_OUT + t0 + t] = outv[co];
        }
    } else {
        // fused final head: gelu(20->128) -> 128->1, sliced to 16384
        __syncthreads();   // all D reads of xs/lxs done
        if (vdB) {
#pragma unroll
            for (int co = 0; co < COH; ++co) xs[cob + co][t] = outv[co];
        }
        __syncthreads();   // layer-3 output visible in xs
        const bool vf = (t < TT2) && (t0 + t < LIN_);
        float* pb = &lxs[0][0];                    // lxs dead -> partial-sum buffer
        if (vf) {
            float xv[CH];
#pragma unroll
            for (int c = 0; c < CH; ++c) xv[c] = xs[c][t];
            const float* w11h  = w11 + (size_t)(half * 64) * CH;   // SGPR base
            const float* wouth = wout + half * 64;
            float partial = 0.f;
#pragma unroll 1
            for (int h = 0; h < 64; h += 2) {
                float hv0 = 0.f, hv1 = 0.f;
#pragma unroll
                for (int c = 0; c < CH; ++c) {
                    hv0 = fmaf(xv[c], w11h[h * CH + c], hv0);
                    hv1 = fmaf(xv[c], w11h[(h + 1) * CH + c], hv1);
                }
                partial = fmaf(gelu_exact(hv0), wouth[h], partial);
                partial = fmaf(gelu_exact(hv1), wouth[h + 1], partial);
            }
            pb[half * 256 + t] = partial;
        }
        __syncthreads();
        if (vf && half == 0)
            xout[(size_t)b * LIN_ + t0 + t] = pb[t] + pb[256 + t];
    }
}

extern "C" void kernel_launch(void* const* d_in, const int* in_sizes, int n_in,
                              void* d_out, int out_size, void* d_ws, size_t ws_size,
                              hipStream_t stream) {
    const float* input   = (const float*)d_in[0];
    const float* w_first = (const float*)d_in[1];
    const float* conv_a  = (const float*)d_in[2];
    const float* conv_b  = (const float*)d_in[3];
    const float* lin_m   = (const float*)d_in[4];
    const float* w11     = (const float*)d_in[5];
    const float* w_out   = (const float*)d_in[6];
    const float* filt_d  = (const float*)d_in[7];
    const float* filt_r  = (const float*)d_in[8];
    float* out = (float*)d_out;

    float* xA = (float*)d_ws;   // intermediate: layer-1 output, 32*20*16410 floats = 42 MB

    {
        dim3 grid(((L0 - 24) + TT2 - 1) / TT2, B_);    // 69 tiles covering 16410
        k_pair<0><<<grid, 512, 0, stream>>>(nullptr, xA, conv_a, conv_b, lin_m,
                                            filt_d, filt_r, input, w_first,
                                            nullptr, nullptr);
    }
    {
        dim3 grid((LIN_ + TT2 - 1) / TT2, B_);         // 69 tiles covering 16384
        k_pair<1><<<grid, 512, 0, stream>>>(xA, out, conv_a, conv_b, lin_m,
                                            filt_d, filt_r, nullptr, nullptr,
                                            w11, w_out);
    }
}